// Round 18
// baseline (342.177 us; speedup 1.0000x reference)
//
#include <hip/hip_runtime.h>
#include <hip/hip_bf16.h>
#include <cstddef>

// R18: VERTICAL FUSION — 13 identical waves; wave w owns tile w (of 13) of
// L0 AND L1 AND L2 (skews 0/1/2). Per iteration each wave runs 3 INDEPENDENT
// chains (frag reads -> MFMA -> cell update) => intra-wave ILP hides ds_read
// and transcendental latency; no role convoy (all waves identical).
// Buffer schedule byte-identical to R17 (verified):
//   H0[2]: L0 reads H0[it&1] (x@g0, h@g1-7), writes h0(it)->H0[(it+1)&1];
//          x(it+1) staged -> H0[(it+1)&1].g0 (wave 12, kg==0 lanes)
//   H1[3]: L1@it (t1=it-1): x-side H0[it&1] (+1g shift), h-side H1[m2],
//          write H1[m1]   (m0=it%3, m1=(it-1)%3, m2=(it-2)%3)
//   H2[2]: L2@it (t2=it-2): x-side H1[m2], h-side H2[(it+1)&1], write H2[it&1]
// Regions: granule = 8k x 16b = 128 shorts; 9 granules/buf; unit u ->
// granule 1+(u>>3) pos u&7; act==1.0 bias col at g7p2 (slot 50); g8 pad.
// Numerics (= R16/R17): fp16 single-term weights/acts, pre-scaled gates
// (i,f,o x -log2e; g x 2log2e), 8-trans fused cell update.

#define T_STEPS 256
#define NITER   258
#define BTOT    4096
#define NTHR    832          // 13 waves
#define GS      128
#define BUFR    1152

typedef __attribute__((ext_vector_type(8))) _Float16 half8;
typedef __attribute__((ext_vector_type(4))) float    f32x4;

#define BAR() do { \
    asm volatile("s_waitcnt lgkmcnt(0)" ::: "memory"); \
    __builtin_amdgcn_sched_barrier(0); \
    __builtin_amdgcn_s_barrier(); \
    __builtin_amdgcn_sched_barrier(0); \
} while (0)

__device__ __forceinline__ unsigned short f2h(float x) {
    union { _Float16 h; unsigned short s; } u;
    u.h = (_Float16)x;
    return u.s;
}

// Pre-scaled 8-trans cell update (= R16/R17).
__device__ __forceinline__ float cell_upd(f32x4 g, float& cst) {
    const float K2 = 2.8853900817779268f;
    float eg  = __builtin_amdgcn_exp2f(fminf(fmaxf(g[2], -126.0f), 126.0f));
    float ei  = __builtin_amdgcn_exp2f(g[0]);
    float ef  = __builtin_amdgcn_exp2f(g[1]);
    float eo  = __builtin_amdgcn_exp2f(g[3]);
    float itg = (eg - 1.0f) * __builtin_amdgcn_rcpf((1.0f + ei) * (1.0f + eg));
    float fg  = __builtin_amdgcn_rcpf(1.0f + ef);
    float c   = fmaf(fg, cst, itg);
    cst = c;
    float ec  = __builtin_amdgcn_exp2f(fminf(fmaxf(K2 * c, -126.0f), 126.0f));
    return (ec - 1.0f) * __builtin_amdgcn_rcpf((1.0f + eo) * (1.0f + ec));
}

// Weight frag loaders (fp16, pre-scaled; runtime tile index).
// L0 k-map: [w_ih(8)@k0-7 | w_hh@k8-57 | bias@58].
__device__ __forceinline__ void load_w0(int T0, int lane,
    const float* __restrict__ w_ih, const float* __restrict__ w_hh,
    const float* __restrict__ b_ih, const float* __restrict__ b_hh,
    half8 (&W)[2])
{
    const float K1 = 1.4426950408889634f, K2 = 2.8853900817779268f;
    const int m = lane & 15, kg = lane >> 4;
    int gp = T0 * 16 + m;
    int gr = (gp < 200) ? ((gp & 3) * 50 + (gp >> 2)) : -1;
    float scale = ((gp & 3) == 2) ? K2 : -K1;
    #pragma unroll
    for (int ks = 0; ks < 2; ++ks)
        #pragma unroll
        for (int e = 0; e < 8; ++e) {
            int k = ks * 32 + kg * 8 + e;
            float v = 0.0f;
            if (gr >= 0) {
                if (k < 8) v = w_ih[gr * 8 + k];
                else if (k < 58) v = w_hh[gr * 50 + (k - 8)];
                else if (k == 58) v = b_ih[gr] + b_hh[gr];
            }
            W[ks][e] = (_Float16)(v * scale);
        }
}
// MID k-map: [w_ih@k0-49 | bias@50 | 0 | w_hh@k64-113 | 0].
__device__ __forceinline__ void load_wm(int T0, int lane,
    const float* __restrict__ w_ih, const float* __restrict__ w_hh,
    const float* __restrict__ b_ih, const float* __restrict__ b_hh,
    half8 (&W)[4])
{
    const float K1 = 1.4426950408889634f, K2 = 2.8853900817779268f;
    const int m = lane & 15, kg = lane >> 4;
    int gp = T0 * 16 + m;
    int gr = (gp < 200) ? ((gp & 3) * 50 + (gp >> 2)) : -1;
    float scale = ((gp & 3) == 2) ? K2 : -K1;
    #pragma unroll
    for (int ks = 0; ks < 4; ++ks)
        #pragma unroll
        for (int e = 0; e < 8; ++e) {
            int k = ks * 32 + kg * 8 + e;
            float v = 0.0f;
            if (gr >= 0) {
                if (k < 50) v = w_ih[gr * 50 + k];
                else if (k == 50) v = b_ih[gr] + b_hh[gr];
                else if (k >= 64 && k < 114) v = w_hh[gr * 50 + (k - 64)];
            }
            W[ks][e] = (_Float16)(v * scale);
        }
}

__global__ __launch_bounds__(NTHR) void lstm_fused(
    const float* __restrict__ xf,
    const float* w_ih0, const float* w_hh0, const float* b_ih0, const float* b_hh0,
    const float* w_ih1, const float* w_hh1, const float* b_ih1, const float* b_hh1,
    const float* w_ih2, const float* w_hh2, const float* b_ih2, const float* b_hh2,
    const float* __restrict__ w_fc, const float* __restrict__ b_fc,
    float* __restrict__ out)
{
    __shared__ __align__(16) short H0[2][BUFR];
    __shared__ __align__(16) short H1[3][BUFR];
    __shared__ __align__(16) short H2[2][BUFR];
    __shared__ __align__(16) float hf[16 * 56];

    const int tid  = threadIdx.x;
    const int lane = tid & 63;
    const int wid  = tid >> 6;          // 0..12 = tile index
    const int b0   = blockIdx.x * 16;

    for (int i = tid; i < 2 * BUFR; i += NTHR) { ((short*)H0)[i] = 0; ((short*)H2)[i] = 0; }
    for (int i = tid; i < 3 * BUFR; i += NTHR) ((short*)H1)[i] = 0;
    __syncthreads();

    // act==1.0 bias columns (g7 p2): H0 both bufs (L0 bias@58, L1 x-side
    // bias@50-shifted), H1 all 3 (L2 x-side bias). x(0) -> H0[0].g0.
    if (tid < 80) {
        int bufi = tid >> 4, b = tid & 15;
        short* bp = (bufi < 2) ? H0[bufi] : H1[bufi - 2];
        bp[7 * GS + b * 8 + 2] = (short)0x3C00;
    }
    if (tid < 16) {
        int b = tid;
        #pragma unroll
        for (int j = 0; j < 8; ++j) {
            float v = xf[((size_t)(b0 + b) * T_STEPS + 0) * 8 + j];
            H0[0][b * 8 + j] = (short)f2h(v);
        }
    }
    __syncthreads();

    const int  T0  = wid;
    const bool XW  = (wid == 12);       // lightest wave stages x
    const int  b   = lane & 15, kg = lane >> 4;
    const bool gok = (T0 < 12) || (kg < 2);
    const int  n   = T0 * 4 + kg;
    const int  wof = (1 + (n >> 3)) * GS + b * 8 + (n & 7);   // h write offset

    half8 W0[2], W1[4], W2[4];
    load_w0(T0, lane, w_ih0, w_hh0, b_ih0, b_hh0, W0);
    load_wm(T0, lane, w_ih1, w_hh1, b_ih1, b_hh1, W1);
    load_wm(T0, lane, w_ih2, w_hh2, b_ih2, b_hh2, W2);
    float c0 = 0.0f, c1 = 0.0f, c2 = 0.0f;
    int m0 = 0, m1 = 2, m2 = 1;         // it%3, (it-1)%3, (it-2)%3

    for (int it = 0; it < NITER; ++it) {
        const int t1 = it - 1, t2 = it - 2;
        const bool d0 = it < T_STEPS;
        const bool d1 = (unsigned)t1 < T_STEPS;
        const bool d2 = (unsigned)t2 < T_STEPS;

        const bool stg = XW && (kg == 0) && (it + 1 < T_STEPS);
        float4 xa, xb;
        if (stg) {
            const float* xr = &xf[((size_t)(b0 + b) * T_STEPS + (it + 1)) * 8];
            xa = *(const float4*)xr;
            xb = *(const float4*)(xr + 4);
        }

        // ---- issue ALL frag reads (3 chains' operands) ----
        half8 A00, A01, A1x0, A1x1, A1h0, A1h1, A2x0, A2x1, A2h0, A2h1;
        if (d0) {
            const short* rb = H0[it & 1];
            A00 = *(const half8*)&rb[kg * GS + b * 8];
            A01 = *(const half8*)&rb[(4 + kg) * GS + b * 8];
        }
        if (d1) {
            const short* xp = H0[it & 1];
            const short* hp = H1[m2];
            A1x0 = *(const half8*)&xp[(1 + kg) * GS + b * 8];
            A1x1 = *(const half8*)&xp[(5 + kg) * GS + b * 8];
            A1h0 = *(const half8*)&hp[(1 + kg) * GS + b * 8];
            A1h1 = *(const half8*)&hp[(5 + kg) * GS + b * 8];
        }
        if (d2) {
            const short* xp = H1[m2];
            const short* hp = H2[(it + 1) & 1];
            A2x0 = *(const half8*)&xp[(1 + kg) * GS + b * 8];
            A2x1 = *(const half8*)&xp[(5 + kg) * GS + b * 8];
            A2h0 = *(const half8*)&hp[(1 + kg) * GS + b * 8];
            A2h1 = *(const half8*)&hp[(5 + kg) * GS + b * 8];
        }

        // ---- MFMA: 3 independent chains (dual-acc on mids) ----
        f32x4 a0  = (f32x4){0.0f, 0.0f, 0.0f, 0.0f};
        f32x4 a1A = a0, a1B = a0, a2A = a0, a2B = a0;
        if (d0) {
            a0 = __builtin_amdgcn_mfma_f32_16x16x32_f16(W0[0], A00, a0, 0, 0, 0);
            a0 = __builtin_amdgcn_mfma_f32_16x16x32_f16(W0[1], A01, a0, 0, 0, 0);
        }
        if (d1) {
            a1A = __builtin_amdgcn_mfma_f32_16x16x32_f16(W1[0], A1x0, a1A, 0, 0, 0);
            a1B = __builtin_amdgcn_mfma_f32_16x16x32_f16(W1[1], A1x1, a1B, 0, 0, 0);
            a1A = __builtin_amdgcn_mfma_f32_16x16x32_f16(W1[2], A1h0, a1A, 0, 0, 0);
            a1B = __builtin_amdgcn_mfma_f32_16x16x32_f16(W1[3], A1h1, a1B, 0, 0, 0);
        }
        if (d2) {
            a2A = __builtin_amdgcn_mfma_f32_16x16x32_f16(W2[0], A2x0, a2A, 0, 0, 0);
            a2B = __builtin_amdgcn_mfma_f32_16x16x32_f16(W2[1], A2x1, a2B, 0, 0, 0);
            a2A = __builtin_amdgcn_mfma_f32_16x16x32_f16(W2[2], A2h0, a2A, 0, 0, 0);
            a2B = __builtin_amdgcn_mfma_f32_16x16x32_f16(W2[3], A2h1, a2B, 0, 0, 0);
        }

        // ---- 3 independent cell updates + single h writes ----
        if (d0 && gok) {
            float h = cell_upd(a0, c0);
            H0[(it + 1) & 1][wof] = (short)f2h(h);
        }
        if (d1 && gok) {
            float h = cell_upd(a1A + a1B, c1);
            H1[m1][wof] = (short)f2h(h);
        }
        if (d2 && gok) {
            float h = cell_upd(a2A + a2B, c2);
            H2[it & 1][wof] = (short)f2h(h);
            if (t2 == T_STEPS - 1) hf[b * 56 + n] = h;
        }
        if (stg) {
            short hi[8];
            hi[0] = (short)f2h(xa.x); hi[1] = (short)f2h(xa.y);
            hi[2] = (short)f2h(xa.z); hi[3] = (short)f2h(xa.w);
            hi[4] = (short)f2h(xb.x); hi[5] = (short)f2h(xb.y);
            hi[6] = (short)f2h(xb.z); hi[7] = (short)f2h(xb.w);
            *(half8*)&H0[(it + 1) & 1][b * 8] = *(half8*)hi;
        }
        BAR();
        int tmp = m2; m2 = m1; m1 = m0; m0 = tmp;
    }

    __syncthreads();

    if (tid < 96) {
        int bb = tid / 6, o = tid - bb * 6;
        float a = b_fc[o];
        #pragma unroll
        for (int u = 0; u < 50; ++u)
            a = fmaf(w_fc[o * 50 + u], hf[bb * 56 + u], a);
        out[(size_t)(b0 + bb) * 6 + o] = a;
    }
}

extern "C" void kernel_launch(void* const* d_in, const int* in_sizes, int n_in,
                              void* d_out, int out_size, void* d_ws, size_t ws_size,
                              hipStream_t stream) {
    (void)in_sizes; (void)n_in; (void)d_ws; (void)ws_size; (void)out_size;

    const float* x     = (const float*)d_in[0];
    const float* w_ih0 = (const float*)d_in[1];
    const float* w_hh0 = (const float*)d_in[2];
    const float* b_ih0 = (const float*)d_in[3];
    const float* b_hh0 = (const float*)d_in[4];
    const float* w_ih1 = (const float*)d_in[5];
    const float* w_hh1 = (const float*)d_in[6];
    const float* b_ih1 = (const float*)d_in[7];
    const float* b_hh1 = (const float*)d_in[8];
    const float* w_ih2 = (const float*)d_in[9];
    const float* w_hh2 = (const float*)d_in[10];
    const float* b_ih2 = (const float*)d_in[11];
    const float* b_hh2 = (const float*)d_in[12];
    const float* w_fc  = (const float*)d_in[13];
    const float* b_fc  = (const float*)d_in[14];
    float* out = (float*)d_out;

    lstm_fused<<<dim3(BTOT / 16), dim3(NTHR), 0, stream>>>(
        x, w_ih0, w_hh0, b_ih0, b_hh0, w_ih1, w_hh1, b_ih1, b_hh1,
        w_ih2, w_hh2, b_ih2, b_hh2, w_fc, b_fc, out);
}

// Round 19
// 246.976 us; speedup vs baseline: 1.3855x; 1.3855x over previous
//
#include <hip/hip_runtime.h>
#include <hip/hip_bf16.h>
#include <cstddef>

// R19 = R17 (fp16 single-term, granule-shared regions, 12 waves, 256us)
// + STATIC STEADY STATE: every role loop is ii(43) x unrolled p(6); since
// all buffer indices have period lcm(2,3)=6 and NITER=258=43*6, the H0/H1/H2
// selects and the m-rotation become COMPILE-TIME constants; invariant lane
// offsets hoisted. Only `it < T_STEPS` guards stay runtime. Otherwise
// byte-identical to R17 (schedule, numerics, cell update).
//
// Schedule recap (verified R11/R17):
//   L0@it (t=it):    read H0[p&1] (x@g0,h@g1-7), write h0 -> H0[(p+1)&1];
//                    x(it+1) staged -> H0[(p+1)&1].g0 (w2, kg==0)
//   L1@it (t=it-1):  x-side H0[p&1] (+1g), h-side H1[(p+1)%3], write H1[(p+2)%3]
//   L2@it (t=it-2):  x-side H1[(p+1)%3], h-side H2[(p+1)&1], write H2[p&1]
// Regions: granule = 8k x 16b = 128 shorts, 9 granules/buf; unit u ->
// g 1+(u>>3) pos u&7; act==1.0 bias col g7p2 (slot 50); g8 pad.
// Numerics: fp16 weights/acts, pre-scaled gates, 8-trans fused update.

#define T_STEPS 256
#define NGRP    43           // 43 * 6 = 258 iterations
#define BTOT    4096
#define NTHR    768
#define GS      128
#define BUFR    1152

typedef __attribute__((ext_vector_type(8))) _Float16 half8;
typedef __attribute__((ext_vector_type(4))) float    f32x4;

#define BAR() do { \
    asm volatile("s_waitcnt lgkmcnt(0)" ::: "memory"); \
    __builtin_amdgcn_sched_barrier(0); \
    __builtin_amdgcn_s_barrier(); \
    __builtin_amdgcn_sched_barrier(0); \
} while (0)

__device__ __forceinline__ unsigned short f2h(float x) {
    union { _Float16 h; unsigned short s; } u;
    u.h = (_Float16)x;
    return u.s;
}

// Pre-scaled 8-trans cell update (= R16/R17).
__device__ __forceinline__ float cell_upd(f32x4 g, float& cst) {
    const float K2 = 2.8853900817779268f;
    float eg  = __builtin_amdgcn_exp2f(fminf(fmaxf(g[2], -126.0f), 126.0f));
    float ei  = __builtin_amdgcn_exp2f(g[0]);
    float ef  = __builtin_amdgcn_exp2f(g[1]);
    float eo  = __builtin_amdgcn_exp2f(g[3]);
    float itg = (eg - 1.0f) * __builtin_amdgcn_rcpf((1.0f + ei) * (1.0f + eg));
    float fg  = __builtin_amdgcn_rcpf(1.0f + ef);
    float c   = fmaf(fg, cst, itg);
    cst = c;
    float ec  = __builtin_amdgcn_exp2f(fminf(fmaxf(K2 * c, -126.0f), 126.0f));
    return (ec - 1.0f) * __builtin_amdgcn_rcpf((1.0f + eo) * (1.0f + ec));
}

// Weights -> fp16 frags, pre-scaled per gate row ((gp&3)==2 -> +K2 else -K1).
template<bool L0M, int NT, int KS>
__device__ __forceinline__ void load_wb(int T0, int lane,
    const float* __restrict__ w_ih, const float* __restrict__ w_hh,
    const float* __restrict__ b_ih, const float* __restrict__ b_hh,
    half8 (&W)[NT][KS])
{
    const float K1 = 1.4426950408889634f, K2 = 2.8853900817779268f;
    const int m = lane & 15, kg = lane >> 4;
    #pragma unroll
    for (int q = 0; q < NT; ++q) {
        int gp = (T0 + q) * 16 + m;
        int gr = (gp < 200) ? ((gp & 3) * 50 + (gp >> 2)) : -1;
        float scale = ((gp & 3) == 2) ? K2 : -K1;
        #pragma unroll
        for (int ks = 0; ks < KS; ++ks)
            #pragma unroll
            for (int e = 0; e < 8; ++e) {
                int k = ks * 32 + kg * 8 + e;
                float v = 0.0f;
                if (gr >= 0) {
                    if (L0M) {
                        if (k < 8) v = w_ih[gr * 8 + k];
                        else if (k < 58) v = w_hh[gr * 50 + (k - 8)];
                        else if (k == 58) v = b_ih[gr] + b_hh[gr];
                    } else {
                        if (k < 50) v = w_ih[gr * 50 + k];
                        else if (k == 50) v = b_ih[gr] + b_hh[gr];
                        else if (k >= 64 && k < 114) v = w_hh[gr * 50 + (k - 64)];
                    }
                }
                W[q][ks][e] = (_Float16)(v * scale);
            }
    }
}

// ---- L0 wave ----
template<int T0, int NT, bool XST>
__device__ void role_l0(int lane, int b0, const float* __restrict__ xf,
    const float* w_ih, const float* w_hh, const float* b_ih, const float* b_hh,
    short (*H0)[BUFR])
{
    half8 W[NT][2];
    load_wb<true, NT, 2>(T0, lane, w_ih, w_hh, b_ih, b_hh, W);
    float cst[NT];
    #pragma unroll
    for (int q = 0; q < NT; ++q) cst[q] = 0.0f;
    const int b = lane & 15, kg = lane >> 4;
    const int o0 = kg * GS + b * 8;            // frag read offsets (invariant)
    const int o4 = (4 + kg) * GS + b * 8;
    int wof[NT];                               // h write offsets (invariant)
    #pragma unroll
    for (int q = 0; q < NT; ++q) {
        int n = (T0 + q) * 4 + kg;
        wof[q] = (1 + (n >> 3)) * GS + b * 8 + (n & 7);
    }

    for (int ii = 0; ii < NGRP; ++ii) {
        #pragma unroll
        for (int p = 0; p < 6; ++p) {
            const int it = ii * 6 + p;
            const bool stg = XST && (kg == 0) && (it + 1 < T_STEPS);
            float4 xa, xb2;
            if (stg) {
                const float* xr = &xf[((size_t)(b0 + b) * T_STEPS + (it + 1)) * 8];
                xa  = *(const float4*)xr;
                xb2 = *(const float4*)(xr + 4);
            }
            if (it < T_STEPS) {
                const short* rb = H0[p & 1];
                short*       wb = H0[(p + 1) & 1];
                half8 A0 = *(const half8*)&rb[o0];
                half8 A1 = *(const half8*)&rb[o4];
                f32x4 accA[NT], accB[NT];
                #pragma unroll
                for (int q = 0; q < NT; ++q) {
                    accA[q] = (f32x4){0.0f, 0.0f, 0.0f, 0.0f};
                    accB[q] = (f32x4){0.0f, 0.0f, 0.0f, 0.0f};
                }
                #pragma unroll
                for (int q = 0; q < NT; ++q)
                    accA[q] = __builtin_amdgcn_mfma_f32_16x16x32_f16(W[q][0], A0, accA[q], 0, 0, 0);
                #pragma unroll
                for (int q = 0; q < NT; ++q)
                    accB[q] = __builtin_amdgcn_mfma_f32_16x16x32_f16(W[q][1], A1, accB[q], 0, 0, 0);
                #pragma unroll
                for (int q = 0; q < NT; ++q) {
                    int n = (T0 + q) * 4 + kg;
                    if (n < 50) {
                        float h = cell_upd(accA[q] + accB[q], cst[q]);
                        wb[wof[q]] = (short)f2h(h);
                    }
                }
            }
            if (stg) {
                short hi[8];
                hi[0] = (short)f2h(xa.x);  hi[1] = (short)f2h(xa.y);
                hi[2] = (short)f2h(xa.z);  hi[3] = (short)f2h(xa.w);
                hi[4] = (short)f2h(xb2.x); hi[5] = (short)f2h(xb2.y);
                hi[6] = (short)f2h(xb2.z); hi[7] = (short)f2h(xb2.w);
                *(half8*)&H0[(p + 1) & 1][b * 8] = *(half8*)hi;
            }
            BAR();
        }
    }
}

// ---- Mid wave, NT=3 ----
template<int T0, bool LASTL>
__device__ void role_mid(int lane,
    const float* w_ih, const float* w_hh, const float* b_ih, const float* b_hh,
    short (*H0)[BUFR], short (*H1)[BUFR], short (*H2)[BUFR], float* hfp)
{
    constexpr int SKEW = LASTL ? 2 : 1;
    half8 W[3][4];
    load_wb<false, 3, 4>(T0, lane, w_ih, w_hh, b_ih, b_hh, W);
    float cst[3] = {0.0f, 0.0f, 0.0f};
    const int b = lane & 15, kg = lane >> 4;
    const int o1 = (1 + kg) * GS + b * 8;
    const int o5 = (5 + kg) * GS + b * 8;
    int wof[3];
    #pragma unroll
    for (int q = 0; q < 3; ++q) {
        int n = (T0 + q) * 4 + kg;
        wof[q] = (1 + (n >> 3)) * GS + b * 8 + (n & 7);
    }

    for (int ii = 0; ii < NGRP; ++ii) {
        #pragma unroll
        for (int p = 0; p < 6; ++p) {
            const int it = ii * 6 + p;
            const int t = it - SKEW;
            if ((unsigned)t < T_STEPS) {
                const short* xsb = LASTL ? H1[(p + 1) % 3] : H0[p & 1];
                const short* hsb = LASTL ? H2[(p + 1) & 1] : H1[(p + 1) % 3];
                short*       wb  = LASTL ? H2[p & 1]       : H1[(p + 2) % 3];

                half8 Ap0 = *(const half8*)&xsb[o1];
                half8 Ap1 = *(const half8*)&xsb[o5];
                half8 Ap2 = *(const half8*)&hsb[o1];
                half8 Ap3 = *(const half8*)&hsb[o5];

                f32x4 accA[3], accB[3];
                #pragma unroll
                for (int q = 0; q < 3; ++q) {
                    accA[q] = (f32x4){0.0f, 0.0f, 0.0f, 0.0f};
                    accB[q] = (f32x4){0.0f, 0.0f, 0.0f, 0.0f};
                }
                #pragma unroll
                for (int q = 0; q < 3; ++q)
                    accA[q] = __builtin_amdgcn_mfma_f32_16x16x32_f16(W[q][0], Ap0, accA[q], 0, 0, 0);
                #pragma unroll
                for (int q = 0; q < 3; ++q)
                    accB[q] = __builtin_amdgcn_mfma_f32_16x16x32_f16(W[q][1], Ap1, accB[q], 0, 0, 0);
                #pragma unroll
                for (int q = 0; q < 3; ++q)
                    accA[q] = __builtin_amdgcn_mfma_f32_16x16x32_f16(W[q][2], Ap2, accA[q], 0, 0, 0);
                #pragma unroll
                for (int q = 0; q < 3; ++q)
                    accB[q] = __builtin_amdgcn_mfma_f32_16x16x32_f16(W[q][3], Ap3, accB[q], 0, 0, 0);

                #pragma unroll
                for (int q = 0; q < 3; ++q) {
                    int n = (T0 + q) * 4 + kg;
                    if (n < 50) {
                        float h = cell_upd(accA[q] + accB[q], cst[q]);
                        wb[wof[q]] = (short)f2h(h);
                        if (LASTL && t == T_STEPS - 1) hfp[b * 56 + n] = h;
                    }
                }
            }
            BAR();
        }
    }
}

// ---- Dual-orphan: L1 tile12 (t1=it-1) + L2 tile12 (t2=it-2), kg<2 ----
__device__ void role_orphan(int lane,
    const float* w_ih1, const float* w_hh1, const float* b_ih1, const float* b_hh1,
    const float* w_ih2, const float* w_hh2, const float* b_ih2, const float* b_hh2,
    short (*H0)[BUFR], short (*H1)[BUFR], short (*H2)[BUFR], float* hfp)
{
    half8 W1[1][4], W2[1][4];
    load_wb<false, 1, 4>(12, lane, w_ih1, w_hh1, b_ih1, b_hh1, W1);
    load_wb<false, 1, 4>(12, lane, w_ih2, w_hh2, b_ih2, b_hh2, W2);
    float c1 = 0.0f, c2 = 0.0f;
    const int b = lane & 15, kg = lane >> 4;
    const int o1 = (1 + kg) * GS + b * 8;
    const int o5 = (5 + kg) * GS + b * 8;
    const int n  = 48 + kg;
    const int wof = (1 + (n >> 3)) * GS + b * 8 + (n & 7);

    for (int ii = 0; ii < NGRP; ++ii) {
        #pragma unroll
        for (int p = 0; p < 6; ++p) {
            const int it = ii * 6 + p;
            const int t1 = it - 1, t2 = it - 2;
            const bool d1 = (unsigned)t1 < T_STEPS, d2 = (unsigned)t2 < T_STEPS;

            half8 A1[4], A2[4];
            if (d1) {
                const short* xsb = H0[p & 1];
                const short* hsb = H1[(p + 1) % 3];
                A1[0] = *(const half8*)&xsb[o1];
                A1[1] = *(const half8*)&xsb[o5];
                A1[2] = *(const half8*)&hsb[o1];
                A1[3] = *(const half8*)&hsb[o5];
            }
            if (d2) {
                const short* xsb = H1[(p + 1) % 3];
                const short* hsb = H2[(p + 1) & 1];
                A2[0] = *(const half8*)&xsb[o1];
                A2[1] = *(const half8*)&xsb[o5];
                A2[2] = *(const half8*)&hsb[o1];
                A2[3] = *(const half8*)&hsb[o5];
            }

            f32x4 a1 = (f32x4){0.0f, 0.0f, 0.0f, 0.0f};
            f32x4 a2 = (f32x4){0.0f, 0.0f, 0.0f, 0.0f};
            #pragma unroll
            for (int ks = 0; ks < 4; ++ks) {
                if (d1) a1 = __builtin_amdgcn_mfma_f32_16x16x32_f16(W1[0][ks], A1[ks], a1, 0, 0, 0);
                if (d2) a2 = __builtin_amdgcn_mfma_f32_16x16x32_f16(W2[0][ks], A2[ks], a2, 0, 0, 0);
            }

            if (d1 && kg < 2) {
                float h = cell_upd(a1, c1);
                H1[(p + 2) % 3][wof] = (short)f2h(h);
            }
            if (d2 && kg < 2) {
                float h = cell_upd(a2, c2);
                H2[p & 1][wof] = (short)f2h(h);
                if (t2 == T_STEPS - 1) hfp[b * 56 + n] = h;
            }
            BAR();
        }
    }
}

__global__ __launch_bounds__(NTHR) void lstm_fused(
    const float* __restrict__ xf,
    const float* w_ih0, const float* w_hh0, const float* b_ih0, const float* b_hh0,
    const float* w_ih1, const float* w_hh1, const float* b_ih1, const float* b_hh1,
    const float* w_ih2, const float* w_hh2, const float* b_ih2, const float* b_hh2,
    const float* __restrict__ w_fc, const float* __restrict__ b_fc,
    float* __restrict__ out)
{
    __shared__ __align__(16) short H0[2][BUFR];
    __shared__ __align__(16) short H1[3][BUFR];
    __shared__ __align__(16) short H2[2][BUFR];
    __shared__ __align__(16) float hf[16 * 56];

    const int tid  = threadIdx.x;
    const int lane = tid & 63;
    const int wid  = tid >> 6;
    const int b0   = blockIdx.x * 16;

    for (int i = tid; i < 2 * BUFR; i += NTHR) { ((short*)H0)[i] = 0; ((short*)H2)[i] = 0; }
    for (int i = tid; i < 3 * BUFR; i += NTHR) ((short*)H1)[i] = 0;
    __syncthreads();

    if (tid < 80) {
        int bufi = tid >> 4, b = tid & 15;
        short* bp = (bufi < 2) ? H0[bufi] : H1[bufi - 2];
        bp[7 * GS + b * 8 + 2] = (short)0x3C00;
    }
    if (tid < 16) {
        int b = tid;
        #pragma unroll
        for (int j = 0; j < 8; ++j) {
            float v = xf[((size_t)(b0 + b) * T_STEPS + 0) * 8 + j];
            H0[0][b * 8 + j] = (short)f2h(v);
        }
    }
    __syncthreads();

    if      (wid == 0)  role_l0<0, 5, false>(lane, b0, xf, w_ih0, w_hh0, b_ih0, b_hh0, H0);
    else if (wid == 1)  role_l0<5, 4, false>(lane, b0, xf, w_ih0, w_hh0, b_ih0, b_hh0, H0);
    else if (wid == 2)  role_l0<9, 4, true >(lane, b0, xf, w_ih0, w_hh0, b_ih0, b_hh0, H0);
    else if (wid == 3)  role_mid<0, false>(lane, w_ih1, w_hh1, b_ih1, b_hh1, H0, H1, H2, nullptr);
    else if (wid == 4)  role_mid<3, false>(lane, w_ih1, w_hh1, b_ih1, b_hh1, H0, H1, H2, nullptr);
    else if (wid == 5)  role_mid<6, false>(lane, w_ih1, w_hh1, b_ih1, b_hh1, H0, H1, H2, nullptr);
    else if (wid == 6)  role_mid<9, false>(lane, w_ih1, w_hh1, b_ih1, b_hh1, H0, H1, H2, nullptr);
    else if (wid == 7)  role_mid<0, true >(lane, w_ih2, w_hh2, b_ih2, b_hh2, H0, H1, H2, hf);
    else if (wid == 8)  role_mid<3, true >(lane, w_ih2, w_hh2, b_ih2, b_hh2, H0, H1, H2, hf);
    else if (wid == 9)  role_mid<6, true >(lane, w_ih2, w_hh2, b_ih2, b_hh2, H0, H1, H2, hf);
    else if (wid == 10) role_mid<9, true >(lane, w_ih2, w_hh2, b_ih2, b_hh2, H0, H1, H2, hf);
    else                role_orphan(lane,
                            w_ih1, w_hh1, b_ih1, b_hh1,
                            w_ih2, w_hh2, b_ih2, b_hh2,
                            H0, H1, H2, hf);

    __syncthreads();

    if (tid < 96) {
        int b = tid / 6, o = tid - b * 6;
        float a = b_fc[o];
        #pragma unroll
        for (int u = 0; u < 50; ++u)
            a = fmaf(w_fc[o * 50 + u], hf[b * 56 + u], a);
        out[(size_t)(b0 + b) * 6 + o] = a;
    }
}

extern "C" void kernel_launch(void* const* d_in, const int* in_sizes, int n_in,
                              void* d_out, int out_size, void* d_ws, size_t ws_size,
                              hipStream_t stream) {
    (void)in_sizes; (void)n_in; (void)d_ws; (void)ws_size; (void)out_size;

    const float* x     = (const float*)d_in[0];
    const float* w_ih0 = (const float*)d_in[1];
    const float* w_hh0 = (const float*)d_in[2];
    const float* b_ih0 = (const float*)d_in[3];
    const float* b_hh0 = (const float*)d_in[4];
    const float* w_ih1 = (const float*)d_in[5];
    const float* w_hh1 = (const float*)d_in[6];
    const float* b_ih1 = (const float*)d_in[7];
    const float* b_hh1 = (const float*)d_in[8];
    const float* w_ih2 = (const float*)d_in[9];
    const float* w_hh2 = (const float*)d_in[10];
    const float* b_ih2 = (const float*)d_in[11];
    const float* b_hh2 = (const float*)d_in[12];
    const float* w_fc  = (const float*)d_in[13];
    const float* b_fc  = (const float*)d_in[14];
    float* out = (float*)d_out;

    lstm_fused<<<dim3(BTOT / 16), dim3(NTHR), 0, stream>>>(
        x, w_ih0, w_hh0, b_ih0, b_hh0, w_ih1, w_hh1, b_ih1, b_hh1,
        w_ih2, w_hh2, b_ih2, b_hh2, w_fc, b_fc, out);
}